// Round 3
// baseline (266.102 us; speedup 1.0000x reference)
//
#include <hip/hip_runtime.h>

// MPS encoder, segmented-chain formulation, register-resident product.
// Per 16-batch tile x 16-site segment: build M_n via fp8 MFMA (M^T into LDS),
// fold into per-wave register product P (packed fp8 dwords) using ds_bpermute
// to synthesize the MFMA B-operand. Combine kernel: one wave per batch.
// Scaling: core8 = fp8(16*core); P stored = 16*true product; combine /16 per seg.

#define NSITES 128
#define FEATD  64
#define BOND   32
#define OUTD   256
#define BT     16
#define SEGLEN 16
#define NSEG   (NSITES / SEGLEN)   // 8
#define NBT    (2048 / BT)         // 128

#define RSTRIDE 48        // LDS row stride (32 B payload + 16 pad)
#define BSTRIDE 1552      // 32*48 + 16 (batch stride, 16B aligned)

typedef __attribute__((ext_vector_type(4))) float float4v;

__device__ __forceinline__ unsigned pk4_fp8(float a, float b, float c, float d) {
    int v = __builtin_amdgcn_cvt_pk_fp8_f32(a, b, 0, false);
    v = __builtin_amdgcn_cvt_pk_fp8_f32(c, d, v, true);
    return (unsigned)v;
}

// cores [n][d][f][r] fp32 -> core8 [n][c=d*32+r][f] fp8 (x16), LDS transpose.
__global__ __launch_bounds__(256)
void prep_cores8(const float* __restrict__ cores, unsigned char* __restrict__ core8) {
    __shared__ float tile[FEATD][BOND + 4];
    const int nd = blockIdx.x;            // n*32 + d
    const int t  = threadIdx.x;
    const float* src = cores + (size_t)nd * (FEATD * BOND);
    {   // coalesced read of the 64x32 fp32 tile (flat = f*32 + r)
        int base = t * 8;
        int f = base >> 5, r0 = base & 31;
        float4 v0 = *(const float4*)(src + base);
        float4 v1 = *(const float4*)(src + base + 4);
        tile[f][r0 + 0] = v0.x; tile[f][r0 + 1] = v0.y;
        tile[f][r0 + 2] = v0.z; tile[f][r0 + 3] = v0.w;
        tile[f][r0 + 4] = v1.x; tile[f][r0 + 5] = v1.y;
        tile[f][r0 + 6] = v1.z; tile[f][r0 + 7] = v1.w;
    }
    __syncthreads();
    const int r = t >> 3, f0 = (t & 7) * 8;
    const float s = 16.0f;
    unsigned lo = pk4_fp8(tile[f0 + 0][r] * s, tile[f0 + 1][r] * s,
                          tile[f0 + 2][r] * s, tile[f0 + 3][r] * s);
    unsigned hi = pk4_fp8(tile[f0 + 4][r] * s, tile[f0 + 5][r] * s,
                          tile[f0 + 6][r] * s, tile[f0 + 7][r] * s);
    uint2 w; w.x = lo; w.y = hi;
    *(uint2*)(core8 + ((size_t)nd * BOND + r) * FEATD + f0) = w;
}

__global__ __launch_bounds__(512, 8)   // force <=64 VGPR -> 4 blocks/CU (32 waves)
void mps_seg(const float* __restrict__ x, const unsigned char* __restrict__ core8,
             unsigned char* __restrict__ Pout) {
    __shared__ __align__(16) unsigned char MS[BT * BSTRIDE];   // 24832 B
    __shared__ __align__(16) unsigned char XS[BT * 72];        //  1152 B

    const int t    = threadIdx.x;
    const int wave = t >> 6;
    const int lane = t & 63;
    const int cl   = lane & 15;
    const int q    = lane >> 4;
    const int b0   = blockIdx.x * BT;
    const int seg  = blockIdx.y;

    // Register-resident product, packed fp8:
    // pw[bi][I][J] = P-bytes [alpha=J*16+cl][beta=I*16+4q .. +3], P = 16*I init.
    int pw[2][2][2];
#pragma unroll
    for (int bi = 0; bi < 2; ++bi)
#pragma unroll
        for (int I = 0; I < 2; ++I)
#pragma unroll
            for (int J = 0; J < 2; ++J) {
                int v = 0;
                int g = cl - 4 * q;
                if (I == J && g >= 0 && g < 4) v = 0x58 << (g * 8);  // fp8(16.0)
                pw[bi][I][J] = v;
            }

    const int xb = t >> 5, xf = (t & 31) * 2;
    float2 xf2 = *(const float2*)(x + ((size_t)(b0 + xb) * NSITES + seg * SEGLEN) * FEATD + xf);
    {   // stage XS for site 0
        int v = __builtin_amdgcn_cvt_pk_fp8_f32(xf2.x, xf2.y, 0, false);
        *(unsigned short*)&XS[xb * 72 + xf] = (unsigned short)(v & 0xffff);
    }

    const int hi32  = (lane & 32) ? 1 : 0;            // q>>1 (dest I select)
    const int addr0 = (cl + ((lane & 16) << 1)) * 4;  // (cl + 32*(q&1))*4
    const int addr1 = addr0 + 64;                     // +16 lanes

    for (int k = 0; k < SEGLEN; ++k) {
        const int n = seg * SEGLEN + k;
        __syncthreads();   // barrier A: XS(k) visible; MS(k-1) reads all done

        const unsigned char* cbase = core8 + (size_t)n * (1024 * FEATD);
        long bx0 = *(const long*)&XS[cl * 72 + q * 8];
        long bx1 = *(const long*)&XS[cl * 72 + 32 + q * 8];

        float2 xn;
        if (k + 1 < SEGLEN)
            xn = *(const float2*)(x + ((size_t)(b0 + xb) * NSITES + n + 1) * FEATD + xf);

        // build M^T in two parity groups (keeps only 4 acc-quads live)
#pragma unroll
        for (int p = 0; p < 2; ++p) {
            long afA[4], afB[4];
#pragma unroll
            for (int u = 0; u < 4; ++u) {
                const unsigned char* ptr =
                    cbase + (size_t)((wave * 8 + 2 * u + p) * 16 + cl) * FEATD + q * 8;
                afA[u] = *(const long*)ptr;
                afB[u] = *(const long*)(ptr + 32);
            }
            float4v acc[4];
#pragma unroll
            for (int u = 0; u < 4; ++u) {
                float4v z = {0.f, 0.f, 0.f, 0.f};
                z = __builtin_amdgcn_mfma_f32_16x16x32_fp8_fp8(afA[u], bx0, z, 0, 0, 0);
                acc[u] = __builtin_amdgcn_mfma_f32_16x16x32_fp8_fp8(afB[u], bx1, z, 0, 0, 0);
            }
#pragma unroll
            for (int g = 0; g < 4; ++g) {
                unsigned w = pk4_fp8(acc[0][g], acc[1][g], acc[2][g], acc[3][g]);
                *(unsigned*)&MS[cl * BSTRIDE + (16 * p + 4 * q + g) * RSTRIDE + wave * 4] = w;
            }
        }

        __syncthreads();   // barrier B: MS(k) visible

        // product: P <- M * P (per batch, per wave), P stays in registers
#pragma unroll
        for (int bi = 0; bi < 2; ++bi) {
            const int bb = wave * 2 + bi;
            long pa0 = *(const long*)&MS[bb * BSTRIDE + (0 * 16 + cl) * RSTRIDE + q * 8];
            long pa1 = *(const long*)&MS[bb * BSTRIDE + (1 * 16 + cl) * RSTRIDE + q * 8];
            long pbv[2];
#pragma unroll
            for (int h = 0; h < 2; ++h) {
                int l0a = __builtin_amdgcn_ds_bpermute(addr0, pw[bi][0][h]);
                int l0b = __builtin_amdgcn_ds_bpermute(addr0, pw[bi][1][h]);
                int l1a = __builtin_amdgcn_ds_bpermute(addr1, pw[bi][0][h]);
                int l1b = __builtin_amdgcn_ds_bpermute(addr1, pw[bi][1][h]);
                int d0 = hi32 ? l0b : l0a;
                int d1 = hi32 ? l1b : l1a;
                pbv[h] = ((long)(unsigned)d0) | (((long)d1) << 32);
            }
            float4v pc[2][2];
#pragma unroll
            for (int I = 0; I < 2; ++I)
#pragma unroll
                for (int J = 0; J < 2; ++J) {
                    float4v z = {0.f, 0.f, 0.f, 0.f};
                    pc[I][J] = __builtin_amdgcn_mfma_f32_16x16x32_fp8_fp8(
                        I ? pa1 : pa0, pbv[J], z, 0, 0, 0);
                }
#pragma unroll
            for (int I = 0; I < 2; ++I)
#pragma unroll
                for (int J = 0; J < 2; ++J)
                    pw[bi][I][J] = (int)pk4_fp8(pc[I][J][0] * 0.0625f, pc[I][J][1] * 0.0625f,
                                                pc[I][J][2] * 0.0625f, pc[I][J][3] * 0.0625f);
        }

        // stage XS for next site (all XS(k) reads happened before barrier B)
        if (k + 1 < SEGLEN) {
            int v = __builtin_amdgcn_cvt_pk_fp8_f32(xn.x, xn.y, 0, false);
            *(unsigned short*)&XS[xb * 72 + xf] = (unsigned short)(v & 0xffff);
        }
    }

    // dump P -> Pout[seg][b][alpha][beta]
#pragma unroll
    for (int bi = 0; bi < 2; ++bi) {
        const int bb = wave * 2 + bi;
        unsigned char* gp = Pout + (((size_t)seg * 2048 + b0 + bb) * 1024);
#pragma unroll
        for (int I = 0; I < 2; ++I)
#pragma unroll
            for (int J = 0; J < 2; ++J)
                *(unsigned*)(gp + (J * 16 + cl) * 32 + I * 16 + q * 4) =
                    (unsigned)pw[bi][I][J];
    }
}

// one wave per batch: res'[beta] = sum_alpha res[alpha] * fp8(P[alpha][beta]) / 16
__global__ __launch_bounds__(512)
void combine(const unsigned char* __restrict__ Pout, const float* __restrict__ startv,
             const float* __restrict__ endv, const float* __restrict__ fc_w,
             const float* __restrict__ fc_b, float* __restrict__ out) {
    const int t    = threadIdx.x;
    const int wave = t >> 6;
    const int lane = t & 63;
    const int r    = lane >> 1;   // beta, duplicated on lane pairs
    const int dh   = lane & 1;    // alpha half
    const int b    = blockIdx.x * 8 + wave;

    float res = startv[r];
    const unsigned char* base = Pout + (size_t)b * 1024 + dh * 512 + r;

    unsigned char by[16];
#pragma unroll
    for (int di = 0; di < 16; ++di) by[di] = base[di * 32];

    for (int s = 0; s < NSEG; ++s) {
        unsigned char by2[16];
        if (s + 1 < NSEG) {
            const unsigned char* nb = base + (size_t)(s + 1) * 2048 * 1024;
#pragma unroll
            for (int di = 0; di < 16; ++di) by2[di] = nb[di * 32];
        }
        float acc = 0.f;
#pragma unroll
        for (int di = 0; di < 16; ++di) {
            float rv = __shfl(res, dh * 32 + di * 2, 64);   // res[alpha], alpha=dh*16+di
            acc += rv * __builtin_amdgcn_cvt_f32_fp8((int)by[di], 0);
        }
        float tot = acc + __shfl_xor(acc, 1, 64);
        res = tot * 0.0625f;
        if (s + 1 < NSEG) {
#pragma unroll
            for (int di = 0; di < 16; ++di) by[di] = by2[di];
        }
    }

    float v = dh ? 0.f : res * endv[r];
#pragma unroll
    for (int off = 1; off < 64; off <<= 1) v += __shfl_xor(v, off, 64);

    const int j = lane * 4;
    float4 w4  = *(const float4*)(fc_w + j);
    float4 bb4 = *(const float4*)(fc_b + j);
    float4 o;
    o.x = v * w4.x + bb4.x;
    o.y = v * w4.y + bb4.y;
    o.z = v * w4.z + bb4.z;
    o.w = v * w4.w + bb4.w;
    *(float4*)(out + (size_t)b * OUTD + j) = o;
}

extern "C" void kernel_launch(void* const* d_in, const int* in_sizes, int n_in,
                              void* d_out, int out_size, void* d_ws, size_t ws_size,
                              hipStream_t stream) {
    const float* x      = (const float*)d_in[0];
    const float* cores  = (const float*)d_in[1];
    const float* startv = (const float*)d_in[2];
    const float* endv   = (const float*)d_in[3];
    const float* fc_w   = (const float*)d_in[4];
    const float* fc_b   = (const float*)d_in[5];
    float* out = (float*)d_out;

    unsigned char* core8 = (unsigned char*)d_ws;                       // 8.4 MB
    unsigned char* Pout  = core8 + (size_t)NSITES * 1024 * FEATD;      // 16.8 MB

    prep_cores8<<<NSITES * BOND, 256, 0, stream>>>(cores, core8);
    mps_seg<<<dim3(NBT, NSEG), 512, 0, stream>>>(x, core8, Pout);
    combine<<<2048 / 8, 512, 0, stream>>>(Pout, startv, endv, fc_w, fc_b, out);
}